// Round 6
// baseline (2771.067 us; speedup 1.0000x reference)
//
#include <hip/hip_runtime.h>
#include <hip/hip_bf16.h>

#define PX 9216      // 96*96
#define LL 9216
#define HALF_L 4608
#define CCH 16       // emitted steps per chunk
#define NCHUNK 576   // 9216/16
#define WARM 96      // burn-in steps (6 chunks of pre-pad)
#define PADC 6       // WARM/CCH
#define NCP  582     // NCHUNK + PADC
#define RS   18624   // 32*NCP (float2 row stride for s)
#define NITER 50

// ws offsets (floats) — ws is 268 MB, no aliasing needed
#define OFF_WC   0        // 32 scaled GRU consts
#define OFF_FLAG 32
#define OFF_HL   40       // 128
#define OFF_W1   192      // 144
#define OFF_B1   336      // 16
#define OFF_W2   384      // 4608
#define OFF_B2   4992     // 32
#define OFF_W3   5024     // 864
#define OFF_B3   5888     // 3
#define OFF_KX   5896     // 9
#define OFF_KY   5908     // 9 (no overlap with KX)
#define OFF_GRAY 8192     // 294912
#define OFF_G    303104   // 294912
#define OFF_MK   598016   // 294912
#define OFF_C1   892928   // 32*16*9216 = 4718592
#define OFF_C2   5611520  // 32*32*9216 = 9437184
#define OFF_YA   15048704 // 16*32*NCP*2 = 595968 (+64 pad)
#define OFF_YB   15644736 // 595968 (+64) ; end 16240768 floats = 65 MB

static __device__ __forceinline__ float ldv(const void* p, long i, bool isb) {
    return isb ? __bfloat162float(((const __hip_bfloat16*)p)[i])
               : ((const float*)p)[i];
}

__global__ __launch_bounds__(256) void k_prep(
    float* __restrict__ ws, const void* img,
    const void* w1, const void* b1, const void* w2, const void* b2,
    const void* w3, const void* b3, const void* kx, const void* ky,
    const void* wih, const void* whh, const void* bih, const void* bhh)
{
    __shared__ float s_isb;
    int t = threadIdx.x;
    if (t == 0) {
        const unsigned short* u16 = (const unsigned short*)img;
        int cnt = 0;
        for (int k = 0; k < 256; ++k) {
            unsigned short u = u16[k];
            int e = (u >> 7) & 0xFF;
            bool ok = (u == 0) || (((u & 0x8000) == 0) && e >= 0x20 && e <= 0x7E);
            cnt += ok ? 1 : 0;
        }
        s_isb = (cnt >= 224) ? 1.f : 0.f;
        ws[OFF_FLAG] = s_isb;
    }
    __syncthreads();
    bool isb = s_isb > 0.5f;

    for (int i = t; i < 144; i += 256) { int co = i/9, tap = i%9; ws[OFF_W1 + tap*16 + co] = ldv(w1,i,isb); }
    for (int i = t; i < 16; i += 256) ws[OFF_B1+i] = ldv(b1,i,isb);
    for (int i = t; i < 4608; i += 256) { int co = i/144, r = i%144, ci = r/9, tap = r%9;
        ws[OFF_W2 + (ci*9+tap)*32 + co] = ldv(w2,i,isb); }
    for (int i = t; i < 32; i += 256) ws[OFF_B2+i] = ldv(b2,i,isb);
    for (int i = t; i < 864; i += 256) { int o = i/288, r = i%288, ci = r/9, tap = r%9;
        ws[OFF_W3 + (ci*9+tap)*3 + o] = ldv(w3,i,isb); }
    for (int i = t; i < 3; i += 256) ws[OFF_B3+i] = ldv(b3,i,isb);
    for (int i = t; i < 9; i += 256) { ws[OFF_KX+i] = ldv(kx,i,isb); ws[OFF_KY+i] = ldv(ky,i,isb); }
    for (int i = t; i < 128; i += 256) ws[OFF_HL+i] = 0.f;
    if (t == 0) {
        const float C1 = 1.4426950408889634f;
        for (int g = 0; g < 4; ++g) {   // r,z gates: sigmoid = rcp(1+exp2(-x*log2e))
            ws[OFF_WC + g*2+0]     = -C1*ldv(wih, g*2+0, isb);
            ws[OFF_WC + g*2+1]     = -C1*ldv(wih, g*2+1, isb);
            ws[OFF_WC + 8 + g*2+0] = -C1*ldv(whh, g*2+0, isb);
            ws[OFF_WC + 8 + g*2+1] = -C1*ldv(whh, g*2+1, isb);
            ws[OFF_WC + 16 + g]    = -C1*(ldv(bih,g,isb)+ldv(bhh,g,isb));
        }
        for (int j = 0; j < 2; ++j) {   // n gate: tanh(t)=1-2/(1+2^(2t*log2e))
            int g = 4+j;
            ws[OFF_WC + 20 + j*2+0] = 2.f*C1*ldv(wih, g*2+0, isb);
            ws[OFF_WC + 20 + j*2+1] = 2.f*C1*ldv(wih, g*2+1, isb);
            ws[OFF_WC + 24 + j*2+0] = 2.f*C1*ldv(whh, g*2+0, isb);
            ws[OFF_WC + 24 + j*2+1] = 2.f*C1*ldv(whh, g*2+1, isb);
            ws[OFF_WC + 28 + j]     = 2.f*C1*ldv(bih, g, isb);
            ws[OFF_WC + 30 + j]     = 2.f*C1*ldv(bhh, g, isb);
        }
    }
}

__global__ __launch_bounds__(256) void k_gray(const void* __restrict__ img,
                                              float* __restrict__ ws)
{
    bool isb = ws[OFF_FLAG] > 0.5f;
    int t = blockIdx.x*256 + threadIdx.x;
    int b = t / PX, p = t - b*PX;
    long base = (long)b*3*PX;
    float r  = ldv(img, base + p, isb);
    float g  = ldv(img, base + PX + p, isb);
    float bl = ldv(img, base + 2*PX + p, isb);
    ws[OFF_GRAY + t] = fmaf(0.2989f, r, fmaf(0.587f, g, 0.114f*bl));
}

__global__ __launch_bounds__(256) void k_sobel(float* __restrict__ ws)
{
    int t = blockIdx.x*256 + threadIdx.x;
    int b = t / PX, p = t - b*PX;
    int y = p / 96, x = p - y*96;
    const float* g = ws + OFF_GRAY + b*PX;
    float gx = 0.f, gy = 0.f;
    #pragma unroll
    for (int dy = 0; dy < 3; ++dy)
    #pragma unroll
    for (int dx = 0; dx < 3; ++dx) {
        int yy = y+dy-1, xx = x+dx-1;
        float v = (yy >= 0 && yy < 96 && xx >= 0 && xx < 96) ? g[yy*96+xx] : 0.f;
        gx = fmaf(v, ws[OFF_KX + dy*3+dx], gx);
        gy = fmaf(v, ws[OFF_KY + dy*3+dx], gy);
    }
    ws[OFF_G + t] = sqrtf(fmaf(gx, gx, gy*gy));
}

__global__ __launch_bounds__(256) void k_conv1(float* __restrict__ ws)
{
    int t = blockIdx.x*256 + threadIdx.x;   // 32*9216 threads
    int bb = t / PX, p = t - bb*PX;
    int y = p / 96, x = p - y*96;
    const float* g = ws + OFF_GRAY + bb*PX;
    float acc[16];
    #pragma unroll
    for (int co = 0; co < 16; ++co) acc[co] = 0.f;
    #pragma unroll
    for (int dy = 0; dy < 3; ++dy)
    #pragma unroll
    for (int dx = 0; dx < 3; ++dx) {
        int yy = y+dy-1, xx = x+dx-1;
        float v = (yy >= 0 && yy < 96 && xx >= 0 && xx < 96) ? g[yy*96+xx] : 0.f;
        const float* w = ws + OFF_W1 + (dy*3+dx)*16;
        #pragma unroll
        for (int co = 0; co < 16; ++co) acc[co] = fmaf(v, w[co], acc[co]);
    }
    float* o = ws + OFF_C1 + bb*16*PX + p;
    #pragma unroll
    for (int co = 0; co < 16; ++co)
        o[co*PX] = fmaxf(acc[co] + ws[OFF_B1+co], 0.f);
}

__global__ __launch_bounds__(256) void k_conv2(float* __restrict__ ws)
{
    __shared__ float tile[16*324];   // 16 ci x 18x18 halo
    int bb = blockIdx.x / 36;        // 32 batches x 36 tiles
    int tI = blockIdx.x % 36;
    int ty0 = (tI / 6) * 16, tx0 = (tI % 6) * 16;
    int t = threadIdx.x;
    for (int i = t; i < 5184; i += 256) {
        int ci = i / 324, r = i - ci*324;
        int yy = r / 18, xx = r - yy*18;
        int gy = ty0 + yy - 1, gx = tx0 + xx - 1;
        float v = 0.f;
        if (gy >= 0 && gy < 96 && gx >= 0 && gx < 96)
            v = ws[OFF_C1 + (bb*16 + ci)*PX + gy*96 + gx];
        tile[i] = v;
    }
    __syncthreads();
    int ty = t / 16, tx = t - (t/16)*16;
    float acc[32];
    #pragma unroll
    for (int co = 0; co < 32; ++co) acc[co] = 0.f;
    for (int ci = 0; ci < 16; ++ci) {
        #pragma unroll
        for (int dy = 0; dy < 3; ++dy)
        #pragma unroll
        for (int dx = 0; dx < 3; ++dx) {
            float v = tile[ci*324 + (ty+dy)*18 + (tx+dx)];
            const float* w = ws + OFF_W2 + (ci*9 + dy*3 + dx)*32;
            #pragma unroll
            for (int co = 0; co < 32; ++co) acc[co] = fmaf(v, w[co], acc[co]);
        }
    }
    int p = (ty0+ty)*96 + tx0 + tx;
    float* o = ws + OFF_C2 + bb*32*PX + p;
    #pragma unroll
    for (int co = 0; co < 32; ++co)
        o[co*PX] = fmaxf(acc[co] + ws[OFF_B2+co], 0.f);
}

__global__ __launch_bounds__(256) void k_conv3(float* __restrict__ ws)
{
    int t = blockIdx.x*256 + threadIdx.x;   // 32*9216
    int bb = t / PX, p = t - bb*PX;
    int y = p / 96, x = p - y*96;
    float a0 = 0.f, a1 = 0.f, a2 = 0.f;
    for (int ci = 0; ci < 32; ++ci) {
        const float* s = ws + OFF_C2 + (bb*32 + ci)*PX;
        #pragma unroll
        for (int dy = 0; dy < 3; ++dy)
        #pragma unroll
        for (int dx = 0; dx < 3; ++dx) {
            int yy = y+dy-1, xx = x+dx-1;
            float v = (yy >= 0 && yy < 96 && xx >= 0 && xx < 96) ? s[yy*96+xx] : 0.f;
            const float* w = ws + OFF_W3 + (ci*9 + dy*3 + dx)*3;
            a0 = fmaf(v, w[0], a0);
            a1 = fmaf(v, w[1], a1);
            a2 = fmaf(v, w[2], a2);
        }
    }
    a0 += ws[OFF_B3+0]; a1 += ws[OFF_B3+1]; a2 += ws[OFF_B3+2];
    int m = 0; float best = a0;
    if (a1 > best) { best = a1; m = 1; }
    if (a2 > best) { m = 2; }
    ws[OFF_MK + bb*PX + p] = (float)m;
}

// pack x=(v0,v1) into transposed layout y[s][b][cp]
__global__ __launch_bounds__(256) void k_pack(float* __restrict__ ws)
{
    int t = blockIdx.x*256 + threadIdx.x;   // 0..294911
    int b = t / LL, l = t - b*LL;
    float v0, v1;
    if (l < HALF_L) {
        const float* m = ws + OFF_MK + b*PX + 2*l;
        v0 = m[0]; v1 = m[1];
    } else {
        const float* g = ws + OFF_G + b*PX + 2*(l - HALF_L);
        v0 = g[0]; v1 = g[1];
    }
    int c = l >> 4, s = l & 15;
    long idx = (long)(s*32 + b)*NCP + c + PADC;
    ((float2*)(ws + OFF_YA))[idx] = make_float2(v0, v1);
}

__global__ __launch_bounds__(1024, 4) void k_gru(const float* __restrict__ ws,
                                                 const float2* __restrict__ S,
                                                 float2* __restrict__ D,
                                                 const float* __restrict__ hlin,
                                                 float* __restrict__ hlout)
{
    int i = blockIdx.x*1024 + threadIdx.x;  // 18432 threads exactly
    int b = i / NCHUNK, c = i - b*NCHUNK;
    float kk[32];
    #pragma unroll
    for (int j = 0; j < 32; ++j) kk[j] = ws[OFF_WC + j];

    int jstar = WARM - c*CCH;               // trip-aligned exact-carry reset point
    float hl0 = hlin[2*b], hl1 = hlin[2*b+1];
    float h0 = 0.f, h1 = 0.f;
    long B0 = (long)b*NCP + c;              // float2 index base

    auto STEP = [&](float v0, float v1) {
        float gr0 = fmaf(kk[0], v0, fmaf(kk[1], v1, kk[16]));
        float gr1 = fmaf(kk[2], v0, fmaf(kk[3], v1, kk[17]));
        float gz0 = fmaf(kk[4], v0, fmaf(kk[5], v1, kk[18]));
        float gz1 = fmaf(kk[6], v0, fmaf(kk[7], v1, kk[19]));
        float gn0 = fmaf(kk[20], v0, fmaf(kk[21], v1, kk[28]));
        float gn1 = fmaf(kk[22], v0, fmaf(kk[23], v1, kk[29]));
        float ar0 = fmaf(kk[8],  h0, fmaf(kk[9],  h1, gr0));
        float ar1 = fmaf(kk[10], h0, fmaf(kk[11], h1, gr1));
        float az0 = fmaf(kk[12], h0, fmaf(kk[13], h1, gz0));
        float az1 = fmaf(kk[14], h0, fmaf(kk[15], h1, gz1));
        float r0 = __builtin_amdgcn_rcpf(1.f + __builtin_amdgcn_exp2f(ar0));
        float r1 = __builtin_amdgcn_rcpf(1.f + __builtin_amdgcn_exp2f(ar1));
        float z0 = __builtin_amdgcn_rcpf(1.f + __builtin_amdgcn_exp2f(az0));
        float z1 = __builtin_amdgcn_rcpf(1.f + __builtin_amdgcn_exp2f(az1));
        float hn0 = fmaf(kk[24], h0, fmaf(kk[25], h1, kk[30]));
        float hn1 = fmaf(kk[26], h0, fmaf(kk[27], h1, kk[31]));
        float u0 = fmaf(r0, hn0, gn0);
        float u1 = fmaf(r1, hn1, gn1);
        float iN0 = __builtin_amdgcn_rcpf(1.f + __builtin_amdgcn_exp2f(u0));
        float iN1 = __builtin_amdgcn_rcpf(1.f + __builtin_amdgcn_exp2f(u1));
        float n0 = fmaf(-2.f, iN0, 1.f);
        float n1 = fmaf(-2.f, iN1, 1.f);
        float omz0 = 1.f - z0, zh0 = z0*h0;
        float omz1 = 1.f - z1, zh1 = z1*h1;
        h0 = fmaf(n0, omz0, zh0);
        h1 = fmaf(n1, omz1, zh1);
    };

    // preload trip 0 (group 0, s=0..3)
    float2 y0 = S[B0 + 0*RS];
    float2 y1 = S[B0 + 1*RS];
    float2 y2 = S[B0 + 2*RS];
    float2 y3 = S[B0 + 3*RS];

    for (int T = 0; T < 28; ++T) {          // 28 trips x 4 steps = 112 steps
        int Tn = T + 1;
        long bn = B0 + (Tn >> 2);           // next trip's group offset
        int sn = (Tn & 3) << 2;
        float2 p0 = S[bn + (sn+0)*(long)RS];
        float2 p1 = S[bn + (sn+1)*(long)RS];
        float2 p2 = S[bn + (sn+2)*(long)RS];
        float2 p3 = S[bn + (sn+3)*(long)RS];
        if (T*4 == jstar) { h0 = hl0; h1 = hl1; }  // exact carry at global l==0
        STEP(y0.x, y0.y); float e00 = fmaxf(h0,0.f), e01 = fmaxf(h1,0.f);
        STEP(y1.x, y1.y); float e10 = fmaxf(h0,0.f), e11 = fmaxf(h1,0.f);
        STEP(y2.x, y2.y); float e20 = fmaxf(h0,0.f), e21 = fmaxf(h1,0.f);
        STEP(y3.x, y3.y); float e30 = fmaxf(h0,0.f), e31 = fmaxf(h1,0.f);
        if (T >= 24) {                      // emit group (g==PADC), wave-uniform
            int s0 = (T & 3) << 2;
            long db = B0 + PADC;
            D[db + (s0+0)*(long)RS] = make_float2(e00, e01);
            D[db + (s0+1)*(long)RS] = make_float2(e10, e11);
            D[db + (s0+2)*(long)RS] = make_float2(e20, e21);
            D[db + (s0+3)*(long)RS] = make_float2(e30, e31);
        }
        y0 = p0; y1 = p1; y2 = p2; y3 = p3;
    }
    if (c == NCHUNK-1) { hlout[2*b] = h0; hlout[2*b+1] = h1; }
}

__global__ __launch_bounds__(256) void k_out(const float* __restrict__ ws,
                                             const void* __restrict__ ow,
                                             const void* __restrict__ ob,
                                             void* __restrict__ out)
{
    bool isb = ws[OFF_FLAG] > 0.5f;
    int t = blockIdx.x*256 + threadIdx.x;
    int b = t / PX, p = t - b*PX;
    int c = p >> 4, s = p & 15;
    float2 v = ((const float2*)(ws + OFF_YA))[(long)(s*32 + b)*NCP + c + PADC];
    #pragma unroll
    for (int o = 0; o < 3; ++o) {
        float w0 = ldv(ow, o*2,   isb);
        float w1 = ldv(ow, o*2+1, isb);
        float bi = ldv(ob, o,     isb);
        float r = fmaf(v.y, w1, fmaf(v.x, w0, bi));
        long idx = (long)(b*3 + o)*PX + p;
        if (isb) ((__hip_bfloat16*)out)[idx] = __float2bfloat16(r);
        else     ((float*)out)[idx] = r;
    }
}

extern "C" void kernel_launch(void* const* d_in, const int* in_sizes, int n_in,
                              void* d_out, int out_size, void* d_ws, size_t ws_size,
                              hipStream_t stream)
{
    (void)in_sizes; (void)n_in; (void)out_size; (void)ws_size;
    float* ws = (float*)d_ws;
    const void* img = d_in[0];
    const void* kx  = d_in[1];
    const void* ky  = d_in[2];
    const void* w1  = d_in[3];
    const void* b1  = d_in[4];
    const void* w2  = d_in[5];
    const void* b2  = d_in[6];
    const void* w3  = d_in[7];
    const void* b3  = d_in[8];
    const void* wih = d_in[9];
    const void* whh = d_in[10];
    const void* bih = d_in[11];
    const void* bhh = d_in[12];
    const void* owp = d_in[13];
    const void* obp = d_in[14];

    k_prep<<<1, 256, 0, stream>>>(ws, img, w1,b1,w2,b2,w3,b3,kx,ky,wih,whh,bih,bhh);
    k_gray<<<1152, 256, 0, stream>>>(img, ws);
    k_sobel<<<1152, 256, 0, stream>>>(ws);
    k_conv1<<<1152, 256, 0, stream>>>(ws);
    k_conv2<<<1152, 256, 0, stream>>>(ws);
    k_conv3<<<1152, 256, 0, stream>>>(ws);
    k_pack<<<1152, 256, 0, stream>>>(ws);

    float2* ya = (float2*)(ws + OFF_YA);
    float2* yb = (float2*)(ws + OFF_YB);
    float* hl = ws + OFF_HL;
    for (int it = 0; it < NITER; ++it) {
        const float2* src = (it & 1) ? (const float2*)yb : (const float2*)ya;
        float2* dst = (it & 1) ? ya : yb;
        k_gru<<<18, 1024, 0, stream>>>(ws, src, dst,
                                       hl + (it & 1)*64, hl + ((it + 1) & 1)*64);
    }
    k_out<<<1152, 256, 0, stream>>>(ws, owp, obp, (void*)d_out);
}

// Round 7
// 933.163 us; speedup vs baseline: 2.9695x; 2.9695x over previous
//
#include <hip/hip_runtime.h>
#include <hip/hip_bf16.h>

#define PX 9216      // 96*96
#define LL 9216
#define HALF_L 4608
#define CCH 16       // emitted steps per chunk
#define NCHUNK 576   // 9216/16
#define WARM 80      // burn-in steps (5 chunks of pre-pad)
#define PADC 5       // WARM/CCH
#define NCP  581     // NCHUNK + PADC
#define RS   18592   // 32*NCP (row stride per s, in elements)
#define NITER 50

// ws offsets (floats)
#define OFF_WC   0        // 32 scaled GRU consts
#define OFF_FLAG 32
#define OFF_HL   40       // 128
#define OFF_W1   192      // 144
#define OFF_B1   336      // 16
#define OFF_W2   384      // 4608
#define OFF_B2   4992     // 32
#define OFF_W3   5024     // 864
#define OFF_B3   5888     // 3
#define OFF_KX   5896     // 9
#define OFF_KY   5908     // 9
#define OFF_C1   8192     // 32*16*9216 = 4718592
#define OFF_C2   4726784  // 32*32*9216 = 9437184
#define OFF_GA4  14163968 // 297472 float4 = 1189888 (+64 pad)
#define OFF_GB4  15353920 // 1189888 (+64)
#define OFF_GA2  16543872 // 297472 float2 = 594944 (+64)
#define OFF_GB2  17138880 // 594944 (+64)
#define OFF_Y2   17733888 // 594944 ; end 18328832 floats = 73 MB

static __device__ __forceinline__ float ldv(const void* p, long i, bool isb) {
    return isb ? __bfloat162float(((const __hip_bfloat16*)p)[i])
               : ((const float*)p)[i];
}

__global__ __launch_bounds__(256) void k_prep(
    float* __restrict__ ws, const void* img,
    const void* w1, const void* b1, const void* w2, const void* b2,
    const void* w3, const void* b3, const void* kx, const void* ky,
    const void* wih, const void* whh, const void* bih, const void* bhh)
{
    __shared__ float s_isb;
    int t = threadIdx.x;
    if (t == 0) {
        const unsigned short* u16 = (const unsigned short*)img;
        int cnt = 0;
        for (int k = 0; k < 256; ++k) {
            unsigned short u = u16[k];
            int e = (u >> 7) & 0xFF;
            bool ok = (u == 0) || (((u & 0x8000) == 0) && e >= 0x20 && e <= 0x7E);
            cnt += ok ? 1 : 0;
        }
        s_isb = (cnt >= 224) ? 1.f : 0.f;
        ws[OFF_FLAG] = s_isb;
    }
    __syncthreads();
    bool isb = s_isb > 0.5f;

    for (int i = t; i < 144; i += 256) { int co = i/9, tap = i%9; ws[OFF_W1 + tap*16 + co] = ldv(w1,i,isb); }
    for (int i = t; i < 16; i += 256) ws[OFF_B1+i] = ldv(b1,i,isb);
    for (int i = t; i < 4608; i += 256) { int co = i/144, r = i%144, ci = r/9, tap = r%9;
        ws[OFF_W2 + (ci*9+tap)*32 + co] = ldv(w2,i,isb); }
    for (int i = t; i < 32; i += 256) ws[OFF_B2+i] = ldv(b2,i,isb);
    for (int i = t; i < 864; i += 256) { int o = i/288, r = i%288, ci = r/9, tap = r%9;
        ws[OFF_W3 + (ci*9+tap)*3 + o] = ldv(w3,i,isb); }
    for (int i = t; i < 3; i += 256) ws[OFF_B3+i] = ldv(b3,i,isb);
    for (int i = t; i < 9; i += 256) { ws[OFF_KX+i] = ldv(kx,i,isb); ws[OFF_KY+i] = ldv(ky,i,isb); }
    for (int i = t; i < 128; i += 256) ws[OFF_HL+i] = 0.f;
    if (t == 0) {
        const float C1 = 1.4426950408889634f;
        for (int g = 0; g < 4; ++g) {   // r,z gates: sigmoid = rcp(1+exp2(-x*log2e))
            ws[OFF_WC + g*2+0]     = -C1*ldv(wih, g*2+0, isb);
            ws[OFF_WC + g*2+1]     = -C1*ldv(wih, g*2+1, isb);
            ws[OFF_WC + 8 + g*2+0] = -C1*ldv(whh, g*2+0, isb);
            ws[OFF_WC + 8 + g*2+1] = -C1*ldv(whh, g*2+1, isb);
            ws[OFF_WC + 16 + g]    = -C1*(ldv(bih,g,isb)+ldv(bhh,g,isb));
        }
        for (int j = 0; j < 2; ++j) {   // n gate: tanh(t)=1-2/(1+2^(2t*log2e))
            int g = 4+j;
            ws[OFF_WC + 20 + j*2+0] = 2.f*C1*ldv(wih, g*2+0, isb);
            ws[OFF_WC + 20 + j*2+1] = 2.f*C1*ldv(wih, g*2+1, isb);
            ws[OFF_WC + 24 + j*2+0] = 2.f*C1*ldv(whh, g*2+0, isb);
            ws[OFF_WC + 24 + j*2+1] = 2.f*C1*ldv(whh, g*2+1, isb);
            ws[OFF_WC + 28 + j]     = 2.f*C1*ldv(bih, g, isb);
            ws[OFF_WC + 30 + j]     = 2.f*C1*ldv(bhh, g, isb);
        }
    }
}

// fused: gray (LDS tile) -> sobel G + conv1 ; packs G half (l>=4608) as gi
__global__ __launch_bounds__(256) void k1(float* __restrict__ ws,
                                          const void* __restrict__ img)
{
    bool isb = ws[OFF_FLAG] > 0.5f;
    __shared__ float gt[324];          // 18x18 gray halo tile
    int bb = blockIdx.x / 36, tI = blockIdx.x % 36;
    int ty0 = (tI / 6) * 16, tx0 = (tI % 6) * 16;
    int t = threadIdx.x;
    long ibase = (long)bb*3*PX;
    for (int i = t; i < 324; i += 256) {
        int yy = i / 18, xx = i - yy*18;
        int gy = ty0 + yy - 1, gx = tx0 + xx - 1;
        float v = 0.f;
        if (gy >= 0 && gy < 96 && gx >= 0 && gx < 96) {
            long pp = gy*96 + gx;
            float r  = ldv(img, ibase + pp, isb);
            float g  = ldv(img, ibase + PX + pp, isb);
            float bl = ldv(img, ibase + 2*PX + pp, isb);
            v = fmaf(0.2989f, r, fmaf(0.587f, g, 0.114f*bl));
        }
        gt[i] = v;
    }
    __syncthreads();
    int ty = t >> 4, tx = t & 15;
    int y = ty0 + ty, x = tx0 + tx, p = y*96 + x;

    float sx = 0.f, sy = 0.f;
    float acc[16];
    #pragma unroll
    for (int co = 0; co < 16; ++co) acc[co] = 0.f;
    #pragma unroll
    for (int dy = 0; dy < 3; ++dy)
    #pragma unroll
    for (int dx = 0; dx < 3; ++dx) {
        float v = gt[(ty+dy)*18 + tx+dx];
        sx = fmaf(v, ws[OFF_KX + dy*3+dx], sx);
        sy = fmaf(v, ws[OFF_KY + dy*3+dx], sy);
        const float* w = ws + OFF_W1 + (dy*3+dx)*16;
        #pragma unroll
        for (int co = 0; co < 16; ++co) acc[co] = fmaf(v, w[co], acc[co]);
    }
    float G = sqrtf(fmaf(sx, sx, sy*sy));
    float* o = ws + OFF_C1 + bb*16*PX + p;
    #pragma unroll
    for (int co = 0; co < 16; ++co)
        o[co*PX] = fmaxf(acc[co] + ws[OFF_B1+co], 0.f);

    float Gn = __shfl_down(G, 1, 64);
    if ((tx & 1) == 0) {
        float v0 = G, v1 = Gn;
        int l = HALF_L + (p >> 1);
        int cc = (l >> 4) + PADC, s = l & 15;
        long idx = (long)(s*32 + bb)*NCP + cc;
        const float* kk = ws + OFF_WC;
        float4 g4;
        g4.x = fmaf(kk[0], v0, fmaf(kk[1], v1, kk[16]));
        g4.y = fmaf(kk[2], v0, fmaf(kk[3], v1, kk[17]));
        g4.z = fmaf(kk[4], v0, fmaf(kk[5], v1, kk[18]));
        g4.w = fmaf(kk[6], v0, fmaf(kk[7], v1, kk[19]));
        float2 g2;
        g2.x = fmaf(kk[20], v0, fmaf(kk[21], v1, kk[28]));
        g2.y = fmaf(kk[22], v0, fmaf(kk[23], v1, kk[29]));
        ((float4*)(ws + OFF_GA4))[idx] = g4;
        ((float2*)(ws + OFF_GA2))[idx] = g2;
    }
}

__global__ __launch_bounds__(256) void k_conv2(float* __restrict__ ws)
{
    __shared__ float tile[16*324];   // 16 ci x 18x18 halo
    int bb = blockIdx.x / 36;
    int tI = blockIdx.x % 36;
    int ty0 = (tI / 6) * 16, tx0 = (tI % 6) * 16;
    int t = threadIdx.x;
    for (int i = t; i < 5184; i += 256) {
        int ci = i / 324, r = i - ci*324;
        int yy = r / 18, xx = r - yy*18;
        int gy = ty0 + yy - 1, gx = tx0 + xx - 1;
        float v = 0.f;
        if (gy >= 0 && gy < 96 && gx >= 0 && gx < 96)
            v = ws[OFF_C1 + (bb*16 + ci)*PX + gy*96 + gx];
        tile[i] = v;
    }
    __syncthreads();
    int ty = t / 16, tx = t - (t/16)*16;
    float acc[32];
    #pragma unroll
    for (int co = 0; co < 32; ++co) acc[co] = 0.f;
    for (int ci = 0; ci < 16; ++ci) {
        #pragma unroll
        for (int dy = 0; dy < 3; ++dy)
        #pragma unroll
        for (int dx = 0; dx < 3; ++dx) {
            float v = tile[ci*324 + (ty+dy)*18 + (tx+dx)];
            const float* w = ws + OFF_W2 + (ci*9 + dy*3 + dx)*32;
            #pragma unroll
            for (int co = 0; co < 32; ++co) acc[co] = fmaf(v, w[co], acc[co]);
        }
    }
    int p = (ty0+ty)*96 + tx0 + tx;
    float* o = ws + OFF_C2 + bb*32*PX + p;
    #pragma unroll
    for (int co = 0; co < 32; ++co)
        o[co*PX] = fmaxf(acc[co] + ws[OFF_B2+co], 0.f);
}

// conv3 + softmax-argmax + marker pack (l<4608) as gi
__global__ __launch_bounds__(256) void k3(float* __restrict__ ws)
{
    int t = blockIdx.x*256 + threadIdx.x;   // 32*9216
    int bb = t / PX, p = t - bb*PX;
    int y = p / 96, x = p - y*96;
    float a0 = 0.f, a1 = 0.f, a2 = 0.f;
    for (int ci = 0; ci < 32; ++ci) {
        const float* s = ws + OFF_C2 + (bb*32 + ci)*PX;
        #pragma unroll
        for (int dy = 0; dy < 3; ++dy)
        #pragma unroll
        for (int dx = 0; dx < 3; ++dx) {
            int yy = y+dy-1, xx = x+dx-1;
            float v = (yy >= 0 && yy < 96 && xx >= 0 && xx < 96) ? s[yy*96+xx] : 0.f;
            const float* w = ws + OFF_W3 + (ci*9 + dy*3 + dx)*3;
            a0 = fmaf(v, w[0], a0);
            a1 = fmaf(v, w[1], a1);
            a2 = fmaf(v, w[2], a2);
        }
    }
    a0 += ws[OFF_B3+0]; a1 += ws[OFF_B3+1]; a2 += ws[OFF_B3+2];
    int mi = 0; float best = a0;
    if (a1 > best) { best = a1; mi = 1; }
    if (a2 > best) { mi = 2; }
    float m = (float)mi;
    float mn = __shfl_down(m, 1, 64);
    if ((p & 1) == 0) {
        float v0 = m, v1 = mn;
        int l = p >> 1;
        int cc = (l >> 4) + PADC, s = l & 15;
        long idx = (long)(s*32 + bb)*NCP + cc;
        const float* kk = ws + OFF_WC;
        float4 g4;
        g4.x = fmaf(kk[0], v0, fmaf(kk[1], v1, kk[16]));
        g4.y = fmaf(kk[2], v0, fmaf(kk[3], v1, kk[17]));
        g4.z = fmaf(kk[4], v0, fmaf(kk[5], v1, kk[18]));
        g4.w = fmaf(kk[6], v0, fmaf(kk[7], v1, kk[19]));
        float2 g2;
        g2.x = fmaf(kk[20], v0, fmaf(kk[21], v1, kk[28]));
        g2.y = fmaf(kk[22], v0, fmaf(kk[23], v1, kk[29]));
        ((float4*)(ws + OFF_GA4))[idx] = g4;
        ((float2*)(ws + OFF_GA2))[idx] = g2;
    }
}

__global__ __launch_bounds__(64) void k_gru(const float* __restrict__ ws,
                                            const float4* __restrict__ S4,
                                            const float2* __restrict__ S2,
                                            float4* __restrict__ D4,
                                            float2* __restrict__ D2,
                                            float2* __restrict__ Y2,
                                            const float* __restrict__ hlin,
                                            float* __restrict__ hlout,
                                            int last)
{
    int i = blockIdx.x*64 + threadIdx.x;    // 18432 threads exactly
    int b = i / NCHUNK, c = i - b*NCHUNK;
    float kk[32];
    #pragma unroll
    for (int j = 0; j < 32; ++j) kk[j] = ws[OFF_WC + j];

    int jstar = WARM - c*CCH;               // trip-aligned exact-carry reset
    float hl0 = hlin[2*b], hl1 = hlin[2*b+1];
    float h0 = 0.f, h1 = 0.f;
    long B0 = (long)b*NCP + c;

    auto STEP = [&](const float4& g4, float gn0, float gn1) {
        float ar0 = fmaf(kk[8],  h0, fmaf(kk[9],  h1, g4.x));
        float ar1 = fmaf(kk[10], h0, fmaf(kk[11], h1, g4.y));
        float az0 = fmaf(kk[12], h0, fmaf(kk[13], h1, g4.z));
        float az1 = fmaf(kk[14], h0, fmaf(kk[15], h1, g4.w));
        float er0 = __builtin_amdgcn_exp2f(ar0);
        float er1 = __builtin_amdgcn_exp2f(ar1);
        float ez0 = __builtin_amdgcn_exp2f(az0);
        float ez1 = __builtin_amdgcn_exp2f(az1);
        float tr0 = 1.f+er0, tr1 = 1.f+er1, tz0 = 1.f+ez0, tz1 = 1.f+ez1;
        float iR = __builtin_amdgcn_rcpf(tr0*tr1);
        float iZ = __builtin_amdgcn_rcpf(tz0*tz1);
        float r0 = iR*tr1, r1 = iR*tr0;
        float z0 = iZ*tz1, z1 = iZ*tz0;
        float omz0 = z0*ez0, omz1 = z1*ez1;   // 1-sigmoid == sigmoid*e
        float zh0 = z0*h0, zh1 = z1*h1;
        float hn0 = fmaf(kk[24], h0, fmaf(kk[25], h1, kk[30]));
        float hn1 = fmaf(kk[26], h0, fmaf(kk[27], h1, kk[31]));
        float u0 = fmaf(r0, hn0, gn0);
        float u1 = fmaf(r1, hn1, gn1);
        float en0 = __builtin_amdgcn_exp2f(u0);
        float en1 = __builtin_amdgcn_exp2f(u1);
        float sn0 = 1.f+en0, sn1 = 1.f+en1;
        float iN = __builtin_amdgcn_rcpf(sn0*sn1);
        float m2 = -2.f*iN;
        float n0 = fmaf(m2, sn1, 1.f);
        float n1 = fmaf(m2, sn0, 1.f);
        h0 = fmaf(n0, omz0, zh0);
        h1 = fmaf(n1, omz1, zh1);
    };

    // preload trip 0
    float4 c40 = S4[B0 + 0*(long)RS], c41 = S4[B0 + 1*(long)RS];
    float4 c42 = S4[B0 + 2*(long)RS], c43 = S4[B0 + 3*(long)RS];
    float2 n2a = S2[B0 + 0*(long)RS], n2b = S2[B0 + 1*(long)RS];
    float2 n2c = S2[B0 + 2*(long)RS], n2d = S2[B0 + 3*(long)RS];
    float2 c2a = n2a, c2b = n2b, c2c = n2c, c2d = n2d;

    for (int T = 0; T < 24; ++T) {          // 24 trips x 4 = 96 steps
        int Tn = T + 1;
        long bn = B0 + (Tn >> 2);
        int sn = (Tn & 3) << 2;
        float4 p0 = S4[bn + (sn+0)*(long)RS];
        float4 p1 = S4[bn + (sn+1)*(long)RS];
        float4 p2 = S4[bn + (sn+2)*(long)RS];
        float4 p3 = S4[bn + (sn+3)*(long)RS];
        float2 q0 = S2[bn + (sn+0)*(long)RS];
        float2 q1 = S2[bn + (sn+1)*(long)RS];
        float2 q2 = S2[bn + (sn+2)*(long)RS];
        float2 q3 = S2[bn + (sn+3)*(long)RS];
        if (4*T == jstar) { h0 = hl0; h1 = hl1; }
        STEP(c40, c2a.x, c2a.y); float a00 = h0, a01 = h1;
        STEP(c41, c2b.x, c2b.y); float a10 = h0, a11 = h1;
        STEP(c42, c2c.x, c2c.y); float a20 = h0, a21 = h1;
        STEP(c43, c2d.x, c2d.y); float a30 = h0, a31 = h1;
        if (T >= 20) {                      // emit (wave-uniform)
            float e00 = fmaxf(a00,0.f), e01 = fmaxf(a01,0.f);
            float e10 = fmaxf(a10,0.f), e11 = fmaxf(a11,0.f);
            float e20 = fmaxf(a20,0.f), e21 = fmaxf(a21,0.f);
            float e30 = fmaxf(a30,0.f), e31 = fmaxf(a31,0.f);
            int s0 = (T & 3) << 2;
            long db = B0 + PADC;
            if (!last) {
                float ee[4][2] = {{e00,e01},{e10,e11},{e20,e21},{e30,e31}};
                #pragma unroll
                for (int k = 0; k < 4; ++k) {
                    float v0 = ee[k][0], v1 = ee[k][1];
                    float4 g4;
                    g4.x = fmaf(kk[0], v0, fmaf(kk[1], v1, kk[16]));
                    g4.y = fmaf(kk[2], v0, fmaf(kk[3], v1, kk[17]));
                    g4.z = fmaf(kk[4], v0, fmaf(kk[5], v1, kk[18]));
                    g4.w = fmaf(kk[6], v0, fmaf(kk[7], v1, kk[19]));
                    float2 g2;
                    g2.x = fmaf(kk[20], v0, fmaf(kk[21], v1, kk[28]));
                    g2.y = fmaf(kk[22], v0, fmaf(kk[23], v1, kk[29]));
                    D4[db + (s0+k)*(long)RS] = g4;
                    D2[db + (s0+k)*(long)RS] = g2;
                }
            } else {
                Y2[db + (s0+0)*(long)RS] = make_float2(e00, e01);
                Y2[db + (s0+1)*(long)RS] = make_float2(e10, e11);
                Y2[db + (s0+2)*(long)RS] = make_float2(e20, e21);
                Y2[db + (s0+3)*(long)RS] = make_float2(e30, e31);
            }
        }
        c40 = p0; c41 = p1; c42 = p2; c43 = p3;
        c2a = q0; c2b = q1; c2c = q2; c2d = q3;
    }
    if (c == NCHUNK-1) { hlout[2*b] = h0; hlout[2*b+1] = h1; }
}

__global__ __launch_bounds__(256) void k_out(const float* __restrict__ ws,
                                             const void* __restrict__ ow,
                                             const void* __restrict__ ob,
                                             void* __restrict__ out)
{
    bool isb = ws[OFF_FLAG] > 0.5f;
    int t = blockIdx.x*256 + threadIdx.x;
    int b = t / PX, p = t - b*PX;
    int cc = (p >> 4) + PADC, s = p & 15;
    float2 v = ((const float2*)(ws + OFF_Y2))[(long)(s*32 + b)*NCP + cc];
    #pragma unroll
    for (int o = 0; o < 3; ++o) {
        float w0 = ldv(ow, o*2,   isb);
        float w1 = ldv(ow, o*2+1, isb);
        float bi = ldv(ob, o,     isb);
        float r = fmaf(v.y, w1, fmaf(v.x, w0, bi));
        long idx = (long)(b*3 + o)*PX + p;
        if (isb) ((__hip_bfloat16*)out)[idx] = __float2bfloat16(r);
        else     ((float*)out)[idx] = r;
    }
}

extern "C" void kernel_launch(void* const* d_in, const int* in_sizes, int n_in,
                              void* d_out, int out_size, void* d_ws, size_t ws_size,
                              hipStream_t stream)
{
    (void)in_sizes; (void)n_in; (void)out_size; (void)ws_size;
    float* ws = (float*)d_ws;
    const void* img = d_in[0];
    const void* kx  = d_in[1];
    const void* ky  = d_in[2];
    const void* w1  = d_in[3];
    const void* b1  = d_in[4];
    const void* w2  = d_in[5];
    const void* b2  = d_in[6];
    const void* w3  = d_in[7];
    const void* b3  = d_in[8];
    const void* wih = d_in[9];
    const void* whh = d_in[10];
    const void* bih = d_in[11];
    const void* bhh = d_in[12];
    const void* owp = d_in[13];
    const void* obp = d_in[14];

    k_prep<<<1, 256, 0, stream>>>(ws, img, w1,b1,w2,b2,w3,b3,kx,ky,wih,whh,bih,bhh);
    k1<<<1152, 256, 0, stream>>>(ws, img);
    k_conv2<<<1152, 256, 0, stream>>>(ws);
    k3<<<1152, 256, 0, stream>>>(ws);

    float4* ga4 = (float4*)(ws + OFF_GA4);
    float4* gb4 = (float4*)(ws + OFF_GB4);
    float2* ga2 = (float2*)(ws + OFF_GA2);
    float2* gb2 = (float2*)(ws + OFF_GB2);
    float2* y2  = (float2*)(ws + OFF_Y2);
    float* hl = ws + OFF_HL;
    for (int it = 0; it < NITER; ++it) {
        const float4* s4 = (it & 1) ? (const float4*)gb4 : (const float4*)ga4;
        const float2* s2 = (it & 1) ? (const float2*)gb2 : (const float2*)ga2;
        float4* d4 = (it & 1) ? ga4 : gb4;
        float2* d2 = (it & 1) ? ga2 : gb2;
        k_gru<<<288, 64, 0, stream>>>(ws, s4, s2, d4, d2, y2,
                                      hl + (it & 1)*64, hl + ((it + 1) & 1)*64,
                                      (it == NITER-1) ? 1 : 0);
    }
    k_out<<<1152, 256, 0, stream>>>(ws, owp, obp, (void*)d_out);
}

// Round 8
// 794.465 us; speedup vs baseline: 3.4880x; 1.1746x over previous
//
#include <hip/hip_runtime.h>
#include <hip/hip_bf16.h>

#define PX 9216      // 96*96
#define LL 9216
#define HALF_L 4608
#define CCH 8        // emitted steps per chunk
#define NCHUNK 1152  // 9216/8
#define WARM 64      // burn-in steps (8 chunks of pre-pad)
#define PADC 8       // WARM/CCH
#define NCP  1160    // NCHUNK + PADC
#define RS   37120   // 32*NCP (row stride per s, in elements)
#define NITER 50

// ws offsets (floats)
#define OFF_WC   0        // 32 scaled GRU consts
#define OFF_FLAG 32
#define OFF_HL   40       // 128
#define OFF_W1   192      // 144
#define OFF_B1   336      // 16
#define OFF_W2   384      // 4608
#define OFF_B2   4992     // 32
#define OFF_W3   5024     // 864
#define OFF_B3   5888     // 3
#define OFF_KX   5896     // 9
#define OFF_KY   5908     // 9
#define OFF_C1   8192     // 32*16*9216 = 4718592
#define OFF_C2   4726784  // 32*32*9216 = 9437184
#define OFF_GA4  14163968 // 8*RS float4 = 1187840 (+64 pad)
#define OFF_GB4  15351872 // 1187904
#define OFF_GA2  16539776 // 8*RS float2 = 593920 (+64)
#define OFF_GB2  17133760 // 593984
#define OFF_Y2   17727744 // 593984 ; end 18321728 floats = 73.3 MB

static __device__ __forceinline__ float ldv(const void* p, long i, bool isb) {
    return isb ? __bfloat162float(((const __hip_bfloat16*)p)[i])
               : ((const float*)p)[i];
}

__global__ __launch_bounds__(256) void k_prep(
    float* __restrict__ ws, const void* img,
    const void* w1, const void* b1, const void* w2, const void* b2,
    const void* w3, const void* b3, const void* kx, const void* ky,
    const void* wih, const void* whh, const void* bih, const void* bhh)
{
    __shared__ float s_isb;
    int t = threadIdx.x;
    if (t == 0) {
        const unsigned short* u16 = (const unsigned short*)img;
        int cnt = 0;
        for (int k = 0; k < 256; ++k) {
            unsigned short u = u16[k];
            int e = (u >> 7) & 0xFF;
            bool ok = (u == 0) || (((u & 0x8000) == 0) && e >= 0x20 && e <= 0x7E);
            cnt += ok ? 1 : 0;
        }
        s_isb = (cnt >= 224) ? 1.f : 0.f;
        ws[OFF_FLAG] = s_isb;
    }
    __syncthreads();
    bool isb = s_isb > 0.5f;

    for (int i = t; i < 144; i += 256) { int co = i/9, tap = i%9; ws[OFF_W1 + tap*16 + co] = ldv(w1,i,isb); }
    for (int i = t; i < 16; i += 256) ws[OFF_B1+i] = ldv(b1,i,isb);
    for (int i = t; i < 4608; i += 256) { int co = i/144, r = i%144, ci = r/9, tap = r%9;
        ws[OFF_W2 + (ci*9+tap)*32 + co] = ldv(w2,i,isb); }
    for (int i = t; i < 32; i += 256) ws[OFF_B2+i] = ldv(b2,i,isb);
    for (int i = t; i < 864; i += 256) { int o = i/288, r = i%288, ci = r/9, tap = r%9;
        ws[OFF_W3 + (ci*9+tap)*3 + o] = ldv(w3,i,isb); }
    for (int i = t; i < 3; i += 256) ws[OFF_B3+i] = ldv(b3,i,isb);
    for (int i = t; i < 9; i += 256) { ws[OFF_KX+i] = ldv(kx,i,isb); ws[OFF_KY+i] = ldv(ky,i,isb); }
    for (int i = t; i < 128; i += 256) ws[OFF_HL+i] = 0.f;
    if (t == 0) {
        const float C1 = 1.4426950408889634f;
        for (int g = 0; g < 4; ++g) {   // r,z gates: sigmoid = rcp(1+exp2(-x*log2e))
            ws[OFF_WC + g*2+0]     = -C1*ldv(wih, g*2+0, isb);
            ws[OFF_WC + g*2+1]     = -C1*ldv(wih, g*2+1, isb);
            ws[OFF_WC + 8 + g*2+0] = -C1*ldv(whh, g*2+0, isb);
            ws[OFF_WC + 8 + g*2+1] = -C1*ldv(whh, g*2+1, isb);
            ws[OFF_WC + 16 + g]    = -C1*(ldv(bih,g,isb)+ldv(bhh,g,isb));
        }
        for (int j = 0; j < 2; ++j) {   // n gate: tanh(t)=1-2/(1+2^(2t*log2e))
            int g = 4+j;
            ws[OFF_WC + 20 + j*2+0] = 2.f*C1*ldv(wih, g*2+0, isb);
            ws[OFF_WC + 20 + j*2+1] = 2.f*C1*ldv(wih, g*2+1, isb);
            ws[OFF_WC + 24 + j*2+0] = 2.f*C1*ldv(whh, g*2+0, isb);
            ws[OFF_WC + 24 + j*2+1] = 2.f*C1*ldv(whh, g*2+1, isb);
            ws[OFF_WC + 28 + j]     = 2.f*C1*ldv(bih, g, isb);
            ws[OFF_WC + 30 + j]     = 2.f*C1*ldv(bhh, g, isb);
        }
    }
}

// fused: gray (LDS tile) -> sobel G + conv1 ; packs G half (l>=4608) as gi
__global__ __launch_bounds__(256) void k1(float* __restrict__ ws,
                                          const void* __restrict__ img)
{
    bool isb = ws[OFF_FLAG] > 0.5f;
    __shared__ float gt[324];          // 18x18 gray halo tile
    int bb = blockIdx.x / 36, tI = blockIdx.x % 36;
    int ty0 = (tI / 6) * 16, tx0 = (tI % 6) * 16;
    int t = threadIdx.x;
    long ibase = (long)bb*3*PX;
    for (int i = t; i < 324; i += 256) {
        int yy = i / 18, xx = i - yy*18;
        int gy = ty0 + yy - 1, gx = tx0 + xx - 1;
        float v = 0.f;
        if (gy >= 0 && gy < 96 && gx >= 0 && gx < 96) {
            long pp = gy*96 + gx;
            float r  = ldv(img, ibase + pp, isb);
            float g  = ldv(img, ibase + PX + pp, isb);
            float bl = ldv(img, ibase + 2*PX + pp, isb);
            v = fmaf(0.2989f, r, fmaf(0.587f, g, 0.114f*bl));
        }
        gt[i] = v;
    }
    __syncthreads();
    int ty = t >> 4, tx = t & 15;
    int y = ty0 + ty, x = tx0 + tx, p = y*96 + x;

    float sx = 0.f, sy = 0.f;
    float acc[16];
    #pragma unroll
    for (int co = 0; co < 16; ++co) acc[co] = 0.f;
    #pragma unroll
    for (int dy = 0; dy < 3; ++dy)
    #pragma unroll
    for (int dx = 0; dx < 3; ++dx) {
        float v = gt[(ty+dy)*18 + tx+dx];
        sx = fmaf(v, ws[OFF_KX + dy*3+dx], sx);
        sy = fmaf(v, ws[OFF_KY + dy*3+dx], sy);
        const float* w = ws + OFF_W1 + (dy*3+dx)*16;
        #pragma unroll
        for (int co = 0; co < 16; ++co) acc[co] = fmaf(v, w[co], acc[co]);
    }
    float G = sqrtf(fmaf(sx, sx, sy*sy));
    float* o = ws + OFF_C1 + bb*16*PX + p;
    #pragma unroll
    for (int co = 0; co < 16; ++co)
        o[co*PX] = fmaxf(acc[co] + ws[OFF_B1+co], 0.f);

    float Gn = __shfl_down(G, 1, 64);
    if ((tx & 1) == 0) {
        float v0 = G, v1 = Gn;
        int l = HALF_L + (p >> 1);
        int cc = (l >> 3) + PADC, s = l & 7;
        long idx = (long)(s*32 + bb)*NCP + cc;
        const float* kk = ws + OFF_WC;
        float4 g4;
        g4.x = fmaf(kk[0], v0, fmaf(kk[1], v1, kk[16]));
        g4.y = fmaf(kk[2], v0, fmaf(kk[3], v1, kk[17]));
        g4.z = fmaf(kk[4], v0, fmaf(kk[5], v1, kk[18]));
        g4.w = fmaf(kk[6], v0, fmaf(kk[7], v1, kk[19]));
        float2 g2;
        g2.x = fmaf(kk[20], v0, fmaf(kk[21], v1, kk[28]));
        g2.y = fmaf(kk[22], v0, fmaf(kk[23], v1, kk[29]));
        ((float4*)(ws + OFF_GA4))[idx] = g4;
        ((float2*)(ws + OFF_GA2))[idx] = g2;
    }
}

__global__ __launch_bounds__(256) void k_conv2(float* __restrict__ ws)
{
    __shared__ float wsm[4608];      // W2 staged: broadcast ds_read, kills VMEM issue
    __shared__ float tile[16*324];   // 16 ci x 18x18 halo
    int bb = blockIdx.x / 36;
    int tI = blockIdx.x % 36;
    int ty0 = (tI / 6) * 16, tx0 = (tI % 6) * 16;
    int t = threadIdx.x;
    for (int i = t; i < 4608; i += 256) wsm[i] = ws[OFF_W2 + i];
    for (int i = t; i < 5184; i += 256) {
        int ci = i / 324, r = i - ci*324;
        int yy = r / 18, xx = r - yy*18;
        int gy = ty0 + yy - 1, gx = tx0 + xx - 1;
        float v = 0.f;
        if (gy >= 0 && gy < 96 && gx >= 0 && gx < 96)
            v = ws[OFF_C1 + (bb*16 + ci)*PX + gy*96 + gx];
        tile[i] = v;
    }
    __syncthreads();
    int ty = t / 16, tx = t - (t/16)*16;
    float acc[32];
    #pragma unroll
    for (int co = 0; co < 32; ++co) acc[co] = 0.f;
    for (int ci = 0; ci < 16; ++ci) {
        #pragma unroll
        for (int dy = 0; dy < 3; ++dy)
        #pragma unroll
        for (int dx = 0; dx < 3; ++dx) {
            float v = tile[ci*324 + (ty+dy)*18 + (tx+dx)];
            const float* w = wsm + (ci*9 + dy*3 + dx)*32;
            #pragma unroll
            for (int co = 0; co < 32; ++co) acc[co] = fmaf(v, w[co], acc[co]);
        }
    }
    int p = (ty0+ty)*96 + tx0 + tx;
    float* o = ws + OFF_C2 + bb*32*PX + p;
    #pragma unroll
    for (int co = 0; co < 32; ++co)
        o[co*PX] = fmaxf(acc[co] + ws[OFF_B2+co], 0.f);
}

// conv3 + softmax-argmax + marker pack (l<4608) as gi
__global__ __launch_bounds__(256) void k3(float* __restrict__ ws)
{
    int t = blockIdx.x*256 + threadIdx.x;   // 32*9216
    int bb = t / PX, p = t - bb*PX;
    int y = p / 96, x = p - y*96;
    float a0 = 0.f, a1 = 0.f, a2 = 0.f;
    for (int ci = 0; ci < 32; ++ci) {
        const float* s = ws + OFF_C2 + (bb*32 + ci)*PX;
        #pragma unroll
        for (int dy = 0; dy < 3; ++dy)
        #pragma unroll
        for (int dx = 0; dx < 3; ++dx) {
            int yy = y+dy-1, xx = x+dx-1;
            float v = (yy >= 0 && yy < 96 && xx >= 0 && xx < 96) ? s[yy*96+xx] : 0.f;
            const float* w = ws + OFF_W3 + (ci*9 + dy*3 + dx)*3;
            a0 = fmaf(v, w[0], a0);
            a1 = fmaf(v, w[1], a1);
            a2 = fmaf(v, w[2], a2);
        }
    }
    a0 += ws[OFF_B3+0]; a1 += ws[OFF_B3+1]; a2 += ws[OFF_B3+2];
    int mi = 0; float best = a0;
    if (a1 > best) { best = a1; mi = 1; }
    if (a2 > best) { mi = 2; }
    float m = (float)mi;
    float mn = __shfl_down(m, 1, 64);
    if ((p & 1) == 0) {
        float v0 = m, v1 = mn;
        int l = p >> 1;
        int cc = (l >> 3) + PADC, s = l & 7;
        long idx = (long)(s*32 + bb)*NCP + cc;
        const float* kk = ws + OFF_WC;
        float4 g4;
        g4.x = fmaf(kk[0], v0, fmaf(kk[1], v1, kk[16]));
        g4.y = fmaf(kk[2], v0, fmaf(kk[3], v1, kk[17]));
        g4.z = fmaf(kk[4], v0, fmaf(kk[5], v1, kk[18]));
        g4.w = fmaf(kk[6], v0, fmaf(kk[7], v1, kk[19]));
        float2 g2;
        g2.x = fmaf(kk[20], v0, fmaf(kk[21], v1, kk[28]));
        g2.y = fmaf(kk[22], v0, fmaf(kk[23], v1, kk[29]));
        ((float4*)(ws + OFF_GA4))[idx] = g4;
        ((float2*)(ws + OFF_GA2))[idx] = g2;
    }
}

__global__ __launch_bounds__(64) void k_gru(const float* __restrict__ ws,
                                            const float4* __restrict__ S4,
                                            const float2* __restrict__ S2,
                                            float4* __restrict__ D4,
                                            float2* __restrict__ D2,
                                            float2* __restrict__ Y2,
                                            const float* __restrict__ hlin,
                                            float* __restrict__ hlout,
                                            int last)
{
    int i = blockIdx.x*64 + threadIdx.x;    // 36864 threads exactly
    int b = i / NCHUNK, c = i - b*NCHUNK;
    float kk[32];
    #pragma unroll
    for (int j = 0; j < 32; ++j) kk[j] = ws[OFF_WC + j];

    int jstar = WARM - c*CCH;               // trip-aligned exact-carry reset
    float hl0 = hlin[2*b], hl1 = hlin[2*b+1];
    float h0 = 0.f, h1 = 0.f;
    long B0 = (long)b*NCP + c;

    auto STEP = [&](const float4& g4, float gn0, float gn1) {
        float ar0 = fmaf(kk[8],  h0, fmaf(kk[9],  h1, g4.x));
        float ar1 = fmaf(kk[10], h0, fmaf(kk[11], h1, g4.y));
        float az0 = fmaf(kk[12], h0, fmaf(kk[13], h1, g4.z));
        float az1 = fmaf(kk[14], h0, fmaf(kk[15], h1, g4.w));
        float er0 = __builtin_amdgcn_exp2f(ar0);
        float er1 = __builtin_amdgcn_exp2f(ar1);
        float ez0 = __builtin_amdgcn_exp2f(az0);
        float ez1 = __builtin_amdgcn_exp2f(az1);
        float tr0 = 1.f+er0, tr1 = 1.f+er1, tz0 = 1.f+ez0, tz1 = 1.f+ez1;
        float iR = __builtin_amdgcn_rcpf(tr0*tr1);
        float iZ = __builtin_amdgcn_rcpf(tz0*tz1);
        float r0 = iR*tr1, r1 = iR*tr0;
        float z0 = iZ*tz1, z1 = iZ*tz0;
        float omz0 = z0*ez0, omz1 = z1*ez1;   // 1-sigmoid == sigmoid*e
        float zh0 = z0*h0, zh1 = z1*h1;
        float hn0 = fmaf(kk[24], h0, fmaf(kk[25], h1, kk[30]));
        float hn1 = fmaf(kk[26], h0, fmaf(kk[27], h1, kk[31]));
        float u0 = fmaf(r0, hn0, gn0);
        float u1 = fmaf(r1, hn1, gn1);
        float en0 = __builtin_amdgcn_exp2f(u0);
        float en1 = __builtin_amdgcn_exp2f(u1);
        float sn0 = 1.f+en0, sn1 = 1.f+en1;
        float iN = __builtin_amdgcn_rcpf(sn0*sn1);
        float m2 = -2.f*iN;
        float n0 = fmaf(m2, sn1, 1.f);
        float n1 = fmaf(m2, sn0, 1.f);
        h0 = fmaf(n0, omz0, zh0);
        h1 = fmaf(n1, omz1, zh1);
    };

    // preload trip 0 (group 0, s=0..3)
    float4 c40 = S4[B0 + 0*(long)RS], c41 = S4[B0 + 1*(long)RS];
    float4 c42 = S4[B0 + 2*(long)RS], c43 = S4[B0 + 3*(long)RS];
    float2 c2a = S2[B0 + 0*(long)RS], c2b = S2[B0 + 1*(long)RS];
    float2 c2c = S2[B0 + 2*(long)RS], c2d = S2[B0 + 3*(long)RS];

    for (int T = 0; T < 18; ++T) {          // 18 trips x 4 = 72 steps
        int Tn = T + 1;
        long bn = B0 + (Tn >> 1);           // group advances every 2 trips
        int sn = (Tn & 1) << 2;
        float4 p0 = S4[bn + (sn+0)*(long)RS];
        float4 p1 = S4[bn + (sn+1)*(long)RS];
        float4 p2 = S4[bn + (sn+2)*(long)RS];
        float4 p3 = S4[bn + (sn+3)*(long)RS];
        float2 q0 = S2[bn + (sn+0)*(long)RS];
        float2 q1 = S2[bn + (sn+1)*(long)RS];
        float2 q2 = S2[bn + (sn+2)*(long)RS];
        float2 q3 = S2[bn + (sn+3)*(long)RS];
        if (4*T == jstar) { h0 = hl0; h1 = hl1; }
        STEP(c40, c2a.x, c2a.y); float a00 = h0, a01 = h1;
        STEP(c41, c2b.x, c2b.y); float a10 = h0, a11 = h1;
        STEP(c42, c2c.x, c2c.y); float a20 = h0, a21 = h1;
        STEP(c43, c2d.x, c2d.y); float a30 = h0, a31 = h1;
        if (T >= 16) {                      // emit last CCH=8 steps (wave-uniform)
            float e00 = fmaxf(a00,0.f), e01 = fmaxf(a01,0.f);
            float e10 = fmaxf(a10,0.f), e11 = fmaxf(a11,0.f);
            float e20 = fmaxf(a20,0.f), e21 = fmaxf(a21,0.f);
            float e30 = fmaxf(a30,0.f), e31 = fmaxf(a31,0.f);
            int s0 = (T & 1) << 2;
            long db = B0 + PADC;
            if (!last) {
                float ee[4][2] = {{e00,e01},{e10,e11},{e20,e21},{e30,e31}};
                #pragma unroll
                for (int k = 0; k < 4; ++k) {
                    float v0 = ee[k][0], v1 = ee[k][1];
                    float4 g4;
                    g4.x = fmaf(kk[0], v0, fmaf(kk[1], v1, kk[16]));
                    g4.y = fmaf(kk[2], v0, fmaf(kk[3], v1, kk[17]));
                    g4.z = fmaf(kk[4], v0, fmaf(kk[5], v1, kk[18]));
                    g4.w = fmaf(kk[6], v0, fmaf(kk[7], v1, kk[19]));
                    float2 g2;
                    g2.x = fmaf(kk[20], v0, fmaf(kk[21], v1, kk[28]));
                    g2.y = fmaf(kk[22], v0, fmaf(kk[23], v1, kk[29]));
                    D4[db + (s0+k)*(long)RS] = g4;
                    D2[db + (s0+k)*(long)RS] = g2;
                }
            } else {
                Y2[db + (s0+0)*(long)RS] = make_float2(e00, e01);
                Y2[db + (s0+1)*(long)RS] = make_float2(e10, e11);
                Y2[db + (s0+2)*(long)RS] = make_float2(e20, e21);
                Y2[db + (s0+3)*(long)RS] = make_float2(e30, e31);
            }
        }
        c40 = p0; c41 = p1; c42 = p2; c43 = p3;
        c2a = q0; c2b = q1; c2c = q2; c2d = q3;
    }
    if (c == NCHUNK-1) { hlout[2*b] = h0; hlout[2*b+1] = h1; }
}

__global__ __launch_bounds__(256) void k_out(const float* __restrict__ ws,
                                             const void* __restrict__ ow,
                                             const void* __restrict__ ob,
                                             void* __restrict__ out)
{
    bool isb = ws[OFF_FLAG] > 0.5f;
    int t = blockIdx.x*256 + threadIdx.x;
    int b = t / PX, p = t - b*PX;
    int cc = (p >> 3) + PADC, s = p & 7;
    float2 v = ((const float2*)(ws + OFF_Y2))[(long)(s*32 + b)*NCP + cc];
    #pragma unroll
    for (int o = 0; o < 3; ++o) {
        float w0 = ldv(ow, o*2,   isb);
        float w1 = ldv(ow, o*2+1, isb);
        float bi = ldv(ob, o,     isb);
        float r = fmaf(v.y, w1, fmaf(v.x, w0, bi));
        long idx = (long)(b*3 + o)*PX + p;
        if (isb) ((__hip_bfloat16*)out)[idx] = __float2bfloat16(r);
        else     ((float*)out)[idx] = r;
    }
}

extern "C" void kernel_launch(void* const* d_in, const int* in_sizes, int n_in,
                              void* d_out, int out_size, void* d_ws, size_t ws_size,
                              hipStream_t stream)
{
    (void)in_sizes; (void)n_in; (void)out_size; (void)ws_size;
    float* ws = (float*)d_ws;
    const void* img = d_in[0];
    const void* kx  = d_in[1];
    const void* ky  = d_in[2];
    const void* w1  = d_in[3];
    const void* b1  = d_in[4];
    const void* w2  = d_in[5];
    const void* b2  = d_in[6];
    const void* w3  = d_in[7];
    const void* b3  = d_in[8];
    const void* wih = d_in[9];
    const void* whh = d_in[10];
    const void* bih = d_in[11];
    const void* bhh = d_in[12];
    const void* owp = d_in[13];
    const void* obp = d_in[14];

    k_prep<<<1, 256, 0, stream>>>(ws, img, w1,b1,w2,b2,w3,b3,kx,ky,wih,whh,bih,bhh);
    k1<<<1152, 256, 0, stream>>>(ws, img);
    k_conv2<<<1152, 256, 0, stream>>>(ws);
    k3<<<1152, 256, 0, stream>>>(ws);

    float4* ga4 = (float4*)(ws + OFF_GA4);
    float4* gb4 = (float4*)(ws + OFF_GB4);
    float2* ga2 = (float2*)(ws + OFF_GA2);
    float2* gb2 = (float2*)(ws + OFF_GB2);
    float2* y2  = (float2*)(ws + OFF_Y2);
    float* hl = ws + OFF_HL;
    for (int it = 0; it < NITER; ++it) {
        const float4* s4 = (it & 1) ? (const float4*)gb4 : (const float4*)ga4;
        const float2* s2 = (it & 1) ? (const float2*)gb2 : (const float2*)ga2;
        float4* d4 = (it & 1) ? ga4 : gb4;
        float2* d2 = (it & 1) ? ga2 : gb2;
        k_gru<<<576, 64, 0, stream>>>(ws, s4, s2, d4, d2, y2,
                                      hl + (it & 1)*64, hl + ((it + 1) & 1)*64,
                                      (it == NITER-1) ? 1 : 0);
    }
    k_out<<<1152, 256, 0, stream>>>(ws, owp, obp, (void*)d_out);
}

// Round 9
// 779.795 us; speedup vs baseline: 3.5536x; 1.0188x over previous
//
#include <hip/hip_runtime.h>
#include <hip/hip_bf16.h>

#define PX 9216      // 96*96
#define LL 9216
#define HALF_L 4608
#define CCH 8        // emitted steps per chunk
#define NCHUNK 1152  // 9216/8
#define WARM 56      // burn-in steps (7 chunks of pre-pad)
#define PADC 7       // WARM/CCH
#define NCP  1159    // NCHUNK + PADC
#define RS   37088   // 32*NCP (row stride per s, in elements)
#define NITER 50

// ws offsets (floats)
#define OFF_WC   0        // 32 scaled GRU consts
#define OFF_FLAG 32
#define OFF_HL   40       // 128
#define OFF_W1   192      // 144
#define OFF_B1   336      // 16
#define OFF_W2   384      // 4608
#define OFF_B2   4992     // 32
#define OFF_W3   5024     // 864
#define OFF_B3   5888     // 3
#define OFF_KX   5896     // 9
#define OFF_KY   5908     // 9
#define OFF_C1   8192     // 32*16*9216 = 4718592
#define OFF_C2   4726784  // 32*32*9216 = 9437184
#define OFF_GA4  14163968 // 8*RS float4 = 1186816 (+64 pad)
#define OFF_GB4  15350848
#define OFF_GA2  16537728 // 8*RS float2 = 593408 (+64)
#define OFF_GB2  17131200
#define OFF_Y2   17724672 // end 18318144 floats = 73.3 MB

static __device__ __forceinline__ float ldv(const void* p, long i, bool isb) {
    return isb ? __bfloat162float(((const __hip_bfloat16*)p)[i])
               : ((const float*)p)[i];
}

__global__ __launch_bounds__(256) void k_prep(
    float* __restrict__ ws, const void* img,
    const void* w1, const void* b1, const void* w2, const void* b2,
    const void* w3, const void* b3, const void* kx, const void* ky,
    const void* wih, const void* whh, const void* bih, const void* bhh)
{
    __shared__ float s_isb;
    int t = threadIdx.x;
    if (t == 0) {
        const unsigned short* u16 = (const unsigned short*)img;
        int cnt = 0;
        for (int k = 0; k < 256; ++k) {
            unsigned short u = u16[k];
            int e = (u >> 7) & 0xFF;
            bool ok = (u == 0) || (((u & 0x8000) == 0) && e >= 0x20 && e <= 0x7E);
            cnt += ok ? 1 : 0;
        }
        s_isb = (cnt >= 224) ? 1.f : 0.f;
        ws[OFF_FLAG] = s_isb;
    }
    __syncthreads();
    bool isb = s_isb > 0.5f;

    for (int i = t; i < 144; i += 256) { int co = i/9, tap = i%9; ws[OFF_W1 + tap*16 + co] = ldv(w1,i,isb); }
    for (int i = t; i < 16; i += 256) ws[OFF_B1+i] = ldv(b1,i,isb);
    for (int i = t; i < 4608; i += 256) { int co = i/144, r = i%144, ci = r/9, tap = r%9;
        ws[OFF_W2 + (ci*9+tap)*32 + co] = ldv(w2,i,isb); }
    for (int i = t; i < 32; i += 256) ws[OFF_B2+i] = ldv(b2,i,isb);
    for (int i = t; i < 864; i += 256) { int o = i/288, r = i%288, ci = r/9, tap = r%9;
        ws[OFF_W3 + (ci*9+tap)*3 + o] = ldv(w3,i,isb); }
    for (int i = t; i < 3; i += 256) ws[OFF_B3+i] = ldv(b3,i,isb);
    for (int i = t; i < 9; i += 256) { ws[OFF_KX+i] = ldv(kx,i,isb); ws[OFF_KY+i] = ldv(ky,i,isb); }
    for (int i = t; i < 128; i += 256) ws[OFF_HL+i] = 0.f;
    if (t == 0) {
        const float C1 = 1.4426950408889634f;
        for (int g = 0; g < 4; ++g) {   // r,z gates: sigmoid = rcp(1+exp2(-x*log2e))
            ws[OFF_WC + g*2+0]     = -C1*ldv(wih, g*2+0, isb);
            ws[OFF_WC + g*2+1]     = -C1*ldv(wih, g*2+1, isb);
            ws[OFF_WC + 8 + g*2+0] = -C1*ldv(whh, g*2+0, isb);
            ws[OFF_WC + 8 + g*2+1] = -C1*ldv(whh, g*2+1, isb);
            ws[OFF_WC + 16 + g]    = -C1*(ldv(bih,g,isb)+ldv(bhh,g,isb));
        }
        for (int j = 0; j < 2; ++j) {   // n gate: tanh(t)=1-2/(1+2^(2t*log2e))
            int g = 4+j;
            ws[OFF_WC + 20 + j*2+0] = 2.f*C1*ldv(wih, g*2+0, isb);
            ws[OFF_WC + 20 + j*2+1] = 2.f*C1*ldv(wih, g*2+1, isb);
            ws[OFF_WC + 24 + j*2+0] = 2.f*C1*ldv(whh, g*2+0, isb);
            ws[OFF_WC + 24 + j*2+1] = 2.f*C1*ldv(whh, g*2+1, isb);
            ws[OFF_WC + 28 + j]     = 2.f*C1*ldv(bih, g, isb);
            ws[OFF_WC + 30 + j]     = 2.f*C1*ldv(bhh, g, isb);
        }
    }
}

// fused: gray (LDS tile) -> sobel G + conv1 ; packs G half (l>=4608) as gi
__global__ __launch_bounds__(256) void k1(float* __restrict__ ws,
                                          const void* __restrict__ img)
{
    bool isb = ws[OFF_FLAG] > 0.5f;
    __shared__ float gt[342];          // 18x18 halo tile, rows padded to 19
    int bb = blockIdx.x / 36, tI = blockIdx.x % 36;
    int ty0 = (tI / 6) * 16, tx0 = (tI % 6) * 16;
    int t = threadIdx.x;
    long ibase = (long)bb*3*PX;
    for (int i = t; i < 324; i += 256) {
        int yy = i / 18, xx = i - yy*18;
        int gy = ty0 + yy - 1, gx = tx0 + xx - 1;
        float v = 0.f;
        if (gy >= 0 && gy < 96 && gx >= 0 && gx < 96) {
            long pp = gy*96 + gx;
            float r  = ldv(img, ibase + pp, isb);
            float g  = ldv(img, ibase + PX + pp, isb);
            float bl = ldv(img, ibase + 2*PX + pp, isb);
            v = fmaf(0.2989f, r, fmaf(0.587f, g, 0.114f*bl));
        }
        gt[yy*19 + xx] = v;
    }
    __syncthreads();
    int ty = t >> 4, tx = t & 15;
    int y = ty0 + ty, x = tx0 + tx, p = y*96 + x;

    float sx = 0.f, sy = 0.f;
    float acc[16];
    #pragma unroll
    for (int co = 0; co < 16; ++co) acc[co] = 0.f;
    #pragma unroll
    for (int dy = 0; dy < 3; ++dy)
    #pragma unroll
    for (int dx = 0; dx < 3; ++dx) {
        float v = gt[(ty+dy)*19 + tx+dx];
        sx = fmaf(v, ws[OFF_KX + dy*3+dx], sx);
        sy = fmaf(v, ws[OFF_KY + dy*3+dx], sy);
        const float* w = ws + OFF_W1 + (dy*3+dx)*16;
        #pragma unroll
        for (int co = 0; co < 16; ++co) acc[co] = fmaf(v, w[co], acc[co]);
    }
    float G = sqrtf(fmaf(sx, sx, sy*sy));
    float* o = ws + OFF_C1 + bb*16*PX + p;
    #pragma unroll
    for (int co = 0; co < 16; ++co)
        o[co*PX] = fmaxf(acc[co] + ws[OFF_B1+co], 0.f);

    float Gn = __shfl_down(G, 1, 64);
    if ((tx & 1) == 0) {
        float v0 = G, v1 = Gn;
        int l = HALF_L + (p >> 1);
        int cc = (l >> 3) + PADC, s = l & 7;
        long idx = (long)(s*32 + bb)*NCP + cc;
        const float* kk = ws + OFF_WC;
        float4 g4;
        g4.x = fmaf(kk[0], v0, fmaf(kk[1], v1, kk[16]));
        g4.y = fmaf(kk[2], v0, fmaf(kk[3], v1, kk[17]));
        g4.z = fmaf(kk[4], v0, fmaf(kk[5], v1, kk[18]));
        g4.w = fmaf(kk[6], v0, fmaf(kk[7], v1, kk[19]));
        float2 g2;
        g2.x = fmaf(kk[20], v0, fmaf(kk[21], v1, kk[28]));
        g2.y = fmaf(kk[22], v0, fmaf(kk[23], v1, kk[29]));
        ((float4*)(ws + OFF_GA4))[idx] = g4;
        ((float2*)(ws + OFF_GA2))[idx] = g2;
    }
}

__global__ __launch_bounds__(256) void k_conv2(float* __restrict__ ws)
{
    __shared__ float tile[16*342];   // 16 ci x 18 rows x 19 (padded)
    int bb = blockIdx.x / 36;
    int tI = blockIdx.x % 36;
    int ty0 = (tI / 6) * 16, tx0 = (tI % 6) * 16;
    int t = threadIdx.x;
    for (int i = t; i < 5184; i += 256) {
        int ci = i / 324, r = i - ci*324;
        int yy = r / 18, xx = r - yy*18;
        int gy = ty0 + yy - 1, gx = tx0 + xx - 1;
        float v = 0.f;
        if (gy >= 0 && gy < 96 && gx >= 0 && gx < 96)
            v = ws[OFF_C1 + (bb*16 + ci)*PX + gy*96 + gx];
        tile[ci*342 + yy*19 + xx] = v;
    }
    __syncthreads();
    int ty = t / 16, tx = t - (t/16)*16;
    float acc[32];
    #pragma unroll
    for (int co = 0; co < 32; ++co) acc[co] = 0.f;
    for (int ci = 0; ci < 16; ++ci) {
        #pragma unroll
        for (int dy = 0; dy < 3; ++dy)
        #pragma unroll
        for (int dx = 0; dx < 3; ++dx) {
            float v = tile[ci*342 + (ty+dy)*19 + (tx+dx)];
            const float* w = ws + OFF_W2 + (ci*9 + dy*3 + dx)*32;
            #pragma unroll
            for (int co = 0; co < 32; ++co) acc[co] = fmaf(v, w[co], acc[co]);
        }
    }
    int p = (ty0+ty)*96 + tx0 + tx;
    float* o = ws + OFF_C2 + bb*32*PX + p;
    #pragma unroll
    for (int co = 0; co < 32; ++co)
        o[co*PX] = fmaxf(acc[co] + ws[OFF_B2+co], 0.f);
}

// conv3 (LDS-tiled) + argmax + marker pack (l<4608) as gi
__global__ __launch_bounds__(256) void k3(float* __restrict__ ws)
{
    __shared__ float tile[32*342];   // 32 ci x 18 rows x 19 (padded) = 43.8 KB
    int bb = blockIdx.x / 36;
    int tI = blockIdx.x % 36;
    int ty0 = (tI / 6) * 16, tx0 = (tI % 6) * 16;
    int t = threadIdx.x;
    for (int i = t; i < 10368; i += 256) {
        int ci = i / 324, r = i - ci*324;
        int yy = r / 18, xx = r - yy*18;
        int gy = ty0 + yy - 1, gx = tx0 + xx - 1;
        float v = 0.f;
        if (gy >= 0 && gy < 96 && gx >= 0 && gx < 96)
            v = ws[OFF_C2 + (bb*32 + ci)*PX + gy*96 + gx];
        tile[ci*342 + yy*19 + xx] = v;
    }
    __syncthreads();
    int ty = t / 16, tx = t - (t/16)*16;
    float a0 = 0.f, a1 = 0.f, a2 = 0.f;
    for (int ci = 0; ci < 32; ++ci) {
        #pragma unroll
        for (int dy = 0; dy < 3; ++dy)
        #pragma unroll
        for (int dx = 0; dx < 3; ++dx) {
            float v = tile[ci*342 + (ty+dy)*19 + (tx+dx)];
            const float* w = ws + OFF_W3 + (ci*9 + dy*3 + dx)*3;
            a0 = fmaf(v, w[0], a0);
            a1 = fmaf(v, w[1], a1);
            a2 = fmaf(v, w[2], a2);
        }
    }
    a0 += ws[OFF_B3+0]; a1 += ws[OFF_B3+1]; a2 += ws[OFF_B3+2];
    int mi = 0; float best = a0;
    if (a1 > best) { best = a1; mi = 1; }
    if (a2 > best) { mi = 2; }
    float m = (float)mi;
    float mn = __shfl_down(m, 1, 64);
    int p = (ty0+ty)*96 + tx0 + tx;
    if ((tx & 1) == 0) {
        float v0 = m, v1 = mn;
        int l = p >> 1;
        int cc = (l >> 3) + PADC, s = l & 7;
        long idx = (long)(s*32 + bb)*NCP + cc;
        const float* kk = ws + OFF_WC;
        float4 g4;
        g4.x = fmaf(kk[0], v0, fmaf(kk[1], v1, kk[16]));
        g4.y = fmaf(kk[2], v0, fmaf(kk[3], v1, kk[17]));
        g4.z = fmaf(kk[4], v0, fmaf(kk[5], v1, kk[18]));
        g4.w = fmaf(kk[6], v0, fmaf(kk[7], v1, kk[19]));
        float2 g2;
        g2.x = fmaf(kk[20], v0, fmaf(kk[21], v1, kk[28]));
        g2.y = fmaf(kk[22], v0, fmaf(kk[23], v1, kk[29]));
        ((float4*)(ws + OFF_GA4))[idx] = g4;
        ((float2*)(ws + OFF_GA2))[idx] = g2;
    }
}

__global__ __launch_bounds__(64) void k_gru(const float* __restrict__ ws,
                                            const float4* __restrict__ S4,
                                            const float2* __restrict__ S2,
                                            float4* __restrict__ D4,
                                            float2* __restrict__ D2,
                                            float2* __restrict__ Y2,
                                            const float* __restrict__ hlin,
                                            float* __restrict__ hlout,
                                            int last)
{
    int i = blockIdx.x*64 + threadIdx.x;    // 36864 threads exactly
    int b = i / NCHUNK, c = i - b*NCHUNK;
    float kk[32];
    #pragma unroll
    for (int j = 0; j < 32; ++j) kk[j] = ws[OFF_WC + j];

    int jstar = WARM - c*CCH;               // trip-aligned exact-carry reset
    float hl0 = hlin[2*b], hl1 = hlin[2*b+1];
    float h0 = 0.f, h1 = 0.f;
    long B0 = (long)b*NCP + c;

    auto STEP = [&](const float4& g4, float gn0, float gn1) {
        float ar0 = fmaf(kk[8],  h0, fmaf(kk[9],  h1, g4.x));
        float ar1 = fmaf(kk[10], h0, fmaf(kk[11], h1, g4.y));
        float az0 = fmaf(kk[12], h0, fmaf(kk[13], h1, g4.z));
        float az1 = fmaf(kk[14], h0, fmaf(kk[15], h1, g4.w));
        float er0 = __builtin_amdgcn_exp2f(ar0);
        float er1 = __builtin_amdgcn_exp2f(ar1);
        float ez0 = __builtin_amdgcn_exp2f(az0);
        float ez1 = __builtin_amdgcn_exp2f(az1);
        float tr0 = 1.f+er0, tr1 = 1.f+er1, tz0 = 1.f+ez0, tz1 = 1.f+ez1;
        float t1 = tr0*tr1, t2 = tz0*tz1;
        float inv = __builtin_amdgcn_rcpf(t1*t2);   // 4-way paired reciprocal
        float i1 = inv*t2, i2 = inv*t1;
        float r0 = i1*tr1, r1 = i1*tr0;
        float z0 = i2*tz1, z1 = i2*tz0;
        float omz0 = z0*ez0, omz1 = z1*ez1;   // 1-sigmoid == sigmoid*e
        float zh0 = z0*h0, zh1 = z1*h1;
        float hn0 = fmaf(kk[24], h0, fmaf(kk[25], h1, kk[30]));
        float hn1 = fmaf(kk[26], h0, fmaf(kk[27], h1, kk[31]));
        float u0 = fmaf(r0, hn0, gn0);
        float u1 = fmaf(r1, hn1, gn1);
        float en0 = __builtin_amdgcn_exp2f(u0);
        float en1 = __builtin_amdgcn_exp2f(u1);
        float sn0 = 1.f+en0, sn1 = 1.f+en1;
        float iN = __builtin_amdgcn_rcpf(sn0*sn1);
        float m2 = -2.f*iN;
        float n0 = fmaf(m2, sn1, 1.f);
        float n1 = fmaf(m2, sn0, 1.f);
        h0 = fmaf(n0, omz0, zh0);
        h1 = fmaf(n1, omz1, zh1);
    };

    // preload trip 0 (group 0, s=0..3)
    float4 c40 = S4[B0 + 0*(long)RS], c41 = S4[B0 + 1*(long)RS];
    float4 c42 = S4[B0 + 2*(long)RS], c43 = S4[B0 + 3*(long)RS];
    float2 c2a = S2[B0 + 0*(long)RS], c2b = S2[B0 + 1*(long)RS];
    float2 c2c = S2[B0 + 2*(long)RS], c2d = S2[B0 + 3*(long)RS];

    for (int T = 0; T < 16; ++T) {          // 16 trips x 4 = 64 steps
        int Tn = T + 1;
        long bn = B0 + (Tn >> 1);           // group advances every 2 trips
        int sn = (Tn & 1) << 2;
        float4 p0 = S4[bn + (sn+0)*(long)RS];
        float4 p1 = S4[bn + (sn+1)*(long)RS];
        float4 p2 = S4[bn + (sn+2)*(long)RS];
        float4 p3 = S4[bn + (sn+3)*(long)RS];
        float2 q0 = S2[bn + (sn+0)*(long)RS];
        float2 q1 = S2[bn + (sn+1)*(long)RS];
        float2 q2 = S2[bn + (sn+2)*(long)RS];
        float2 q3 = S2[bn + (sn+3)*(long)RS];
        if (4*T == jstar) { h0 = hl0; h1 = hl1; }
        STEP(c40, c2a.x, c2a.y); float a00 = h0, a01 = h1;
        STEP(c41, c2b.x, c2b.y); float a10 = h0, a11 = h1;
        STEP(c42, c2c.x, c2c.y); float a20 = h0, a21 = h1;
        STEP(c43, c2d.x, c2d.y); float a30 = h0, a31 = h1;
        if (T >= 14) {                      // emit last CCH=8 steps (wave-uniform)
            float e00 = fmaxf(a00,0.f), e01 = fmaxf(a01,0.f);
            float e10 = fmaxf(a10,0.f), e11 = fmaxf(a11,0.f);
            float e20 = fmaxf(a20,0.f), e21 = fmaxf(a21,0.f);
            float e30 = fmaxf(a30,0.f), e31 = fmaxf(a31,0.f);
            int s0 = (T & 1) << 2;
            long db = B0 + PADC;
            if (!last) {
                float ee[4][2] = {{e00,e01},{e10,e11},{e20,e21},{e30,e31}};
                #pragma unroll
                for (int k = 0; k < 4; ++k) {
                    float v0 = ee[k][0], v1 = ee[k][1];
                    float4 g4;
                    g4.x = fmaf(kk[0], v0, fmaf(kk[1], v1, kk[16]));
                    g4.y = fmaf(kk[2], v0, fmaf(kk[3], v1, kk[17]));
                    g4.z = fmaf(kk[4], v0, fmaf(kk[5], v1, kk[18]));
                    g4.w = fmaf(kk[6], v0, fmaf(kk[7], v1, kk[19]));
                    float2 g2;
                    g2.x = fmaf(kk[20], v0, fmaf(kk[21], v1, kk[28]));
                    g2.y = fmaf(kk[22], v0, fmaf(kk[23], v1, kk[29]));
                    D4[db + (s0+k)*(long)RS] = g4;
                    D2[db + (s0+k)*(long)RS] = g2;
                }
            } else {
                Y2[db + (s0+0)*(long)RS] = make_float2(e00, e01);
                Y2[db + (s0+1)*(long)RS] = make_float2(e10, e11);
                Y2[db + (s0+2)*(long)RS] = make_float2(e20, e21);
                Y2[db + (s0+3)*(long)RS] = make_float2(e30, e31);
            }
        }
        c40 = p0; c41 = p1; c42 = p2; c43 = p3;
        c2a = q0; c2b = q1; c2c = q2; c2d = q3;
    }
    if (c == NCHUNK-1) { hlout[2*b] = h0; hlout[2*b+1] = h1; }
}

__global__ __launch_bounds__(256) void k_out(const float* __restrict__ ws,
                                             const void* __restrict__ ow,
                                             const void* __restrict__ ob,
                                             void* __restrict__ out)
{
    bool isb = ws[OFF_FLAG] > 0.5f;
    int t = blockIdx.x*256 + threadIdx.x;
    int b = t / PX, p = t - b*PX;
    int cc = (p >> 3) + PADC, s = p & 7;
    float2 v = ((const float2*)(ws + OFF_Y2))[(long)(s*32 + b)*NCP + cc];
    #pragma unroll
    for (int o = 0; o < 3; ++o) {
        float w0 = ldv(ow, o*2,   isb);
        float w1 = ldv(ow, o*2+1, isb);
        float bi = ldv(ob, o,     isb);
        float r = fmaf(v.y, w1, fmaf(v.x, w0, bi));
        long idx = (long)(b*3 + o)*PX + p;
        if (isb) ((__hip_bfloat16*)out)[idx] = __float2bfloat16(r);
        else     ((float*)out)[idx] = r;
    }
}

extern "C" void kernel_launch(void* const* d_in, const int* in_sizes, int n_in,
                              void* d_out, int out_size, void* d_ws, size_t ws_size,
                              hipStream_t stream)
{
    (void)in_sizes; (void)n_in; (void)out_size; (void)ws_size;
    float* ws = (float*)d_ws;
    const void* img = d_in[0];
    const void* kx  = d_in[1];
    const void* ky  = d_in[2];
    const void* w1  = d_in[3];
    const void* b1  = d_in[4];
    const void* w2  = d_in[5];
    const void* b2  = d_in[6];
    const void* w3  = d_in[7];
    const void* b3  = d_in[8];
    const void* wih = d_in[9];
    const void* whh = d_in[10];
    const void* bih = d_in[11];
    const void* bhh = d_in[12];
    const void* owp = d_in[13];
    const void* obp = d_in[14];

    k_prep<<<1, 256, 0, stream>>>(ws, img, w1,b1,w2,b2,w3,b3,kx,ky,wih,whh,bih,bhh);
    k1<<<1152, 256, 0, stream>>>(ws, img);
    k_conv2<<<1152, 256, 0, stream>>>(ws);
    k3<<<1152, 256, 0, stream>>>(ws);

    float4* ga4 = (float4*)(ws + OFF_GA4);
    float4* gb4 = (float4*)(ws + OFF_GB4);
    float2* ga2 = (float2*)(ws + OFF_GA2);
    float2* gb2 = (float2*)(ws + OFF_GB2);
    float2* y2  = (float2*)(ws + OFF_Y2);
    float* hl = ws + OFF_HL;
    for (int it = 0; it < NITER; ++it) {
        const float4* s4 = (it & 1) ? (const float4*)gb4 : (const float4*)ga4;
        const float2* s2 = (it & 1) ? (const float2*)gb2 : (const float2*)ga2;
        float4* d4 = (it & 1) ? ga4 : gb4;
        float2* d2 = (it & 1) ? ga2 : gb2;
        k_gru<<<576, 64, 0, stream>>>(ws, s4, s2, d4, d2, y2,
                                      hl + (it & 1)*64, hl + ((it + 1) & 1)*64,
                                      (it == NITER-1) ? 1 : 0);
    }
    k_out<<<1152, 256, 0, stream>>>(ws, owp, obp, (void*)d_out);
}